// Round 9
// baseline (1264.764 us; speedup 1.0000x reference)
//
#include <hip/hip_runtime.h>

#define DD   128
#define NL   8000
#define NC   16000
#define TSTEPS 8
#define NBF  2     // steps 0..1 bf16 6-term; steps 2..7 fp16 3-term
#define ROWW 96    // max clauses per literal (mean 40, std 6.3)
#define COLW 64    // max literals per clause (mean 20, std 4.4)

// clause kernels: 32-row tiles, K=256 -> 32 octs, stride 33 short8 (pad)
#define OS   33
#define SPLITS8 (32 * OS)        // oct-slots per plane = 1056
#define SPLIT   (SPLITS8 * 8)    // shorts per plane = 8448
// literal bf16 kernel: 16-row tiles, K=384 -> 48 octs, stride 17 short8
#define LSTR 17
#define LSPL (48 * LSTR * 8)     // shorts per plane = 6528
// literal fp16 kernel: 32-row tiles, K=384 -> 48 octs, stride 33 short8
#define L2S  33
#define L2SPL (48 * L2S * 8)     // shorts per plane = 12672

typedef __attribute__((ext_vector_type(8))) short  short8;
typedef __attribute__((ext_vector_type(8))) _Float16 half8;
typedef __attribute__((ext_vector_type(4))) float  f32x4;

__device__ __forceinline__ float frcp(float x) { return __builtin_amdgcn_rcpf(x); }
__device__ __forceinline__ float sigm(float x) { return frcp(1.f + __expf(-x)); }
__device__ __forceinline__ float tanh_(float x) {
  float e = __expf(2.f * x);
  return 1.f - 2.f * frcp(e + 1.f);
}
__device__ __forceinline__ void add4(float4& a, const float4 b) {
  a.x += b.x; a.y += b.y; a.z += b.z; a.w += b.w;
}
__device__ __forceinline__ unsigned short bfround(float v) {  // RNE fp32 -> bf16
  unsigned u = __float_as_uint(v);
  return (unsigned short)((u + 0x7FFF + ((u >> 16) & 1)) >> 16);
}
__device__ __forceinline__ float bf2f(unsigned short b) {
  return __uint_as_float(((unsigned)b) << 16);
}
__device__ __forceinline__ void splitf16(float v, unsigned short& h, unsigned short& l) {
  _Float16 hh = (_Float16)v;           // RNE
  float r = v - (float)hh;             // exact
  _Float16 ll = (_Float16)r;
  h = __builtin_bit_cast(unsigned short, hh);
  l = __builtin_bit_cast(unsigned short, ll);
}
__device__ __forceinline__ int4 packi4(const unsigned short* p) {
  return make_int4(p[0] | ((int)p[1] << 16), p[2] | ((int)p[3] << 16),
                   p[4] | ((int)p[5] << 16), p[6] | ((int)p[7] << 16));
}

// bf16 triple-split 8 floats -> 3 octets, clause layout (stride OS, plane SPLIT)
__device__ __forceinline__ void store_oct3(unsigned short* A, int oct, int m,
                                           float4 a, float4 b) {
  float f[8] = {a.x, a.y, a.z, a.w, b.x, b.y, b.z, b.w};
  unsigned short h[8], md[8], lo[8];
  #pragma unroll
  for (int j = 0; j < 8; ++j) {
    h[j] = bfround(f[j]);
    float r1 = f[j] - bf2f(h[j]);       // exact (Sterbenz)
    md[j] = bfround(r1);
    float r2 = r1 - bf2f(md[j]);        // exact
    lo[j] = bfround(r2);
  }
  int base = (oct * OS + m) * 8;
  *(int4*)(A + base)             = packi4(h);
  *(int4*)(A + SPLIT + base)     = packi4(md);
  *(int4*)(A + 2 * SPLIT + base) = packi4(lo);
}

// fp16 2-split 8 floats -> 2 octets, generic layout (strideS8 slots, plane in shorts)
__device__ __forceinline__ void store_oct2g(unsigned short* A, int strideS8, int plane,
                                            int oct, int m, float4 a, float4 b) {
  float f[8] = {a.x, a.y, a.z, a.w, b.x, b.y, b.z, b.w};
  unsigned short h[8], lo[8];
  #pragma unroll
  for (int j = 0; j < 8; ++j) splitf16(f[j], h[j], lo[j]);
  int base = (oct * strideS8 + m) * 8;
  *(int4*)(A + base)         = packi4(h);
  *(int4*)(A + plane + base) = packi4(lo);
}

// bf16 triple-split 4 floats -> half-octet, 16-row literal layout
__device__ __forceinline__ void store_half3L(unsigned short* A, int oct, int half, int m,
                                             float4 a) {
  float f[4] = {a.x, a.y, a.z, a.w};
  unsigned short h[4], md[4], lo[4];
  #pragma unroll
  for (int j = 0; j < 4; ++j) {
    h[j] = bfround(f[j]);
    float r1 = f[j] - bf2f(h[j]);
    md[j] = bfround(r1);
    float r2 = r1 - bf2f(md[j]);
    lo[j] = bfround(r2);
  }
  int base = (oct * LSTR + m) * 8 + half * 4;
  *(int2*)(A + base)            = make_int2(h[0]  | ((int)h[1]  << 16), h[2]  | ((int)h[3]  << 16));
  *(int2*)(A + LSPL + base)     = make_int2(md[0] | ((int)md[1] << 16), md[2] | ((int)md[3] << 16));
  *(int2*)(A + 2 * LSPL + base) = make_int2(lo[0] | ((int)lo[1] << 16), lo[2] | ((int)lo[3] << 16));
}

__device__ __forceinline__ void split_store_bf3(float w, int idx, unsigned short* hi,
                                                unsigned short* md, unsigned short* lo) {
  unsigned short h = bfround(w);
  float r1 = w - bf2f(h);
  unsigned short m = bfround(r1);
  float r2 = r1 - bf2f(m);
  hi[idx] = h; md[idx] = m; lo[idx] = bfround(r2);
}

// 6-term bf16 triple-split product (error ~2^-27)
#define MFMA6(ACC, AH, AM, AL, BH, BM, BL)                                   \
  ACC = __builtin_amdgcn_mfma_f32_16x16x32_bf16(AH, BH, ACC, 0, 0, 0);       \
  ACC = __builtin_amdgcn_mfma_f32_16x16x32_bf16(AH, BM, ACC, 0, 0, 0);       \
  ACC = __builtin_amdgcn_mfma_f32_16x16x32_bf16(AM, BH, ACC, 0, 0, 0);       \
  ACC = __builtin_amdgcn_mfma_f32_16x16x32_bf16(AH, BL, ACC, 0, 0, 0);       \
  ACC = __builtin_amdgcn_mfma_f32_16x16x32_bf16(AL, BH, ACC, 0, 0, 0);       \
  ACC = __builtin_amdgcn_mfma_f32_16x16x32_bf16(AM, BM, ACC, 0, 0, 0);

// 3-term fp16 2-split product (R8: +matched-prediction win). Dropped AL*BL is
// <= 2^-22*|A||B|, same order as the fp16-split representation residual.
#define MFMA3(ACC, AH, AL, BH, BL)                                           \
  ACC = __builtin_amdgcn_mfma_f32_16x16x32_f16(AH, BH, ACC, 0, 0, 0);        \
  ACC = __builtin_amdgcn_mfma_f32_16x16x32_f16(AH, BL, ACC, 0, 0, 0);        \
  ACC = __builtin_amdgcn_mfma_f32_16x16x32_f16(AL, BH, ACC, 0, 0, 0);

// ---------------- fused preprocessing ----------------
// R8: build_all runs FIRST and also zeroes rcnt/ccnt (it doesn't read them);
// the dispatch boundary before prep_graph is the required sync. Removes the
// hipMemsetAsync dispatch entirely: 19 -> 18 dispatches.
__global__ __launch_bounds__(256) void build_all(
    const float* __restrict__ WihC, const float* __restrict__ Wlc,
    const float* __restrict__ WhhC, const float* __restrict__ blc,
    const float* __restrict__ bihC, const float* __restrict__ bhhC,
    const float* __restrict__ WihL, const float* __restrict__ Wcl,
    const float* __restrict__ WhhL, const float* __restrict__ bcl,
    const float* __restrict__ bihL, const float* __restrict__ bhhL,
    unsigned short* __restrict__ pkChi, unsigned short* __restrict__ pkCmd,
    unsigned short* __restrict__ pkClo,
    unsigned short* __restrict__ qkChi, unsigned short* __restrict__ qkClo,
    unsigned short* __restrict__ pkLhi, unsigned short* __restrict__ pkLmd,
    unsigned short* __restrict__ pkLlo,
    unsigned short* __restrict__ qkLhi, unsigned short* __restrict__ qkLlo,
    float* __restrict__ bsumC, float* __restrict__ bvecC,
    float* __restrict__ bsumL, float* __restrict__ bvecL,
    int* __restrict__ rcnt /* rcnt|ccnt contiguous, NL+NC ints */) {
  const int b = blockIdx.x, t = threadIdx.x;
  // counter zeroing, grid-strided across all blocks (disjoint from pack writes)
  for (int j = b * 256 + t; j < NL + NC; j += 1284 * 256) rcnt[j] = 0;

  if (b < 512) {            // clause pack: B[k][n]
    int i = b * 256 + t;
    int k = i >> 9, n = i & 511;
    float w;
    if (k < 128) {
      float s = 0.f;
      for (int d = 0; d < 128; ++d) s += WihC[n * 128 + d] * Wlc[d * 128 + k];
      w = s;
    } else {
      w = WhhC[n * 128 + (k - 128)];
    }
    int idx = ((k >> 3) * 512 + n) * 8 + (k & 7);
    split_store_bf3(w, idx, pkChi, pkCmd, pkClo);
    splitf16(w, qkChi[idx], qkClo[idx]);
  } else if (b < 1280) {    // literal pack
    int i = (b - 512) * 256 + t;
    int k = i >> 9, n = i & 511;
    float w;
    if (k < 128) {
      float s = 0.f;
      for (int d = 0; d < 128; ++d) s += WihL[n * 256 + d] * Wcl[d * 128 + k];
      w = s;
    } else if (k < 256) {
      w = WihL[n * 256 + k];
    } else {
      w = WhhL[n * 128 + (k - 256)];
    }
    int idx = ((k >> 3) * 512 + n) * 8 + (k & 7);
    split_store_bf3(w, idx, pkLhi, pkLmd, pkLlo);
    splitf16(w, qkLhi[idx], qkLlo[idx]);
  } else {                  // biases: blocks 1280..1283, i in [0,1024)
    int i = (b - 1280) * 256 + t;
    if (i < 512) {
      bsumC[i] = bihC[i] + bhhC[i];
      float s = 0.f;
      for (int d = 0; d < 128; ++d) s += WihC[i * 128 + d] * blc[d];
      bvecC[i] = s;
    } else if (i < 1024) {
      int n = i - 512;
      bsumL[n] = bihL[n] + bhhL[n];
      float s = 0.f;
      for (int d = 0; d < 128; ++d) s += WihL[n * 256 + d] * bcl[d];
      bvecL[n] = s;
    }
  }
}

// init_states + scan_M fused (R7, proven): disjoint outputs, one dispatch.
__global__ __launch_bounds__(256) void prep_graph(
    float4* __restrict__ Lbuf, const float4* __restrict__ L0,
    float4* __restrict__ hL, const float4* __restrict__ hL0,
    float4* __restrict__ hC, const float4* __restrict__ hC0,
    const float4* __restrict__ M4,
    int* __restrict__ csr, int* __restrict__ csc,
    int* __restrict__ rcnt, int* __restrict__ ccnt) {
  int i = blockIdx.x * 256 + threadIdx.x, stride = gridDim.x * 256;
  for (int j = i; j < NL * DD / 4; j += stride) { Lbuf[j] = L0[j]; hL[j] = hL0[j]; }
  for (int j = i; j < NC * DD / 4; j += stride) hC[j] = hC0[j];

  // one pass over M (512 MB): padded-ELL both directions
  const int total = (NL * NC) / 4;
  for (int idx = i; idx < total; idx += stride) {
    float4 v = M4[idx];
    if (v.x == 0.f && v.y == 0.f && v.z == 0.f && v.w == 0.f) continue;
    int base = idx * 4;
    int l = base / NC;
    int c0 = base - l * NC;
    float vv[4] = {v.x, v.y, v.z, v.w};
    #pragma unroll
    for (int e = 0; e < 4; ++e) {
      if (vv[e] != 0.f) {
        int c = c0 + e;
        int rp = atomicAdd(&rcnt[l], 1);
        if (rp < ROWW) csr[l * ROWW + rp] = c;
        int cp = atomicAdd(&ccnt[c], 1);
        if (cp < COLW) csc[c * COLW + cp] = l;
      }
    }
  }
}

// ---------------- shared epilogues ----------------
// LAST: final step -> skip the dead hC/hL state store (nothing reads it again).
template <bool LAST = false>
__device__ __forceinline__ void clause_epilogue(
    const f32x4 acc[2][4], const float* bsum, const float* bvec, const int* ccnt,
    float* hC, float* Cs, int rowBase, int quad, int cw) {
  float bs_[4], bv_[4];
  #pragma unroll
  for (int g = 0; g < 4; ++g) { bs_[g] = bsum[g * 128 + cw]; bv_[g] = bvec[g * 128 + cw]; }
  #pragma unroll
  for (int mt = 0; mt < 2; ++mt) {
    #pragma unroll
    for (int reg = 0; reg < 4; ++reg) {
      int row = rowBase + mt * 16 + quad * 4 + reg;
      float deg = (float)ccnt[row];
      float co = hC[(size_t)row * DD + cw];
      float iv = acc[mt][0][reg] + bs_[0] + deg * bv_[0];
      float fv = acc[mt][1][reg] + bs_[1] + deg * bv_[1];
      float gv = acc[mt][2][reg] + bs_[2] + deg * bv_[2];
      float ov = acc[mt][3][reg] + bs_[3] + deg * bv_[3];
      float cn = sigm(fv) * co + sigm(iv) * tanh_(gv);
      if constexpr (!LAST) hC[(size_t)row * DD + cw] = cn;
      Cs[(size_t)row * DD + cw] = sigm(ov) * tanh_(cn);
    }
  }
}

template <bool LAST = false>
__device__ __forceinline__ void literal_epilogue2(
    const f32x4 acc[2][4], const float* bsum, const float* bvec, const int* rcnt,
    float* hL, float* Lbuf, int rowBase, int quad, int cw) {
  float bs_[4], bv_[4];
  #pragma unroll
  for (int g = 0; g < 4; ++g) { bs_[g] = bsum[g * 128 + cw]; bv_[g] = bvec[g * 128 + cw]; }
  #pragma unroll
  for (int mt = 0; mt < 2; ++mt) {
    #pragma unroll
    for (int reg = 0; reg < 4; ++reg) {
      int row = rowBase + mt * 16 + quad * 4 + reg;
      float deg = (float)rcnt[row];
      float co = hL[(size_t)row * DD + cw];
      float iv = acc[mt][0][reg] + bs_[0] + deg * bv_[0];
      float fv = acc[mt][1][reg] + bs_[1] + deg * bv_[1];
      float gv = acc[mt][2][reg] + bs_[2] + deg * bv_[2];
      float ov = acc[mt][3][reg] + bs_[3] + deg * bv_[3];
      float cn = sigm(fv) * co + sigm(iv) * tanh_(gv);
      if constexpr (!LAST) hL[(size_t)row * DD + cw] = cn;
      Lbuf[(size_t)row * DD + cw] = sigm(ov) * tanh_(cn);
    }
  }
}

// ---------------- bf16 6-term step kernels (steps 0..NBF-1) ----------------
// Proven R2 structure: 512 threads, (512,2), setprio.

template <int NOCT, bool STAGE_H>
__global__ __launch_bounds__(512, 2) void clause_bf3(
    const float* __restrict__ Lbuf, const int* __restrict__ csc, const int* __restrict__ ccnt,
    const unsigned short* __restrict__ pkhi, const unsigned short* __restrict__ pkmd,
    const unsigned short* __restrict__ pklo,
    const float* __restrict__ bsum, const float* __restrict__ bvec,
    float* __restrict__ hC, float* __restrict__ Cs) {
  __shared__ unsigned short A[3 * SPLIT];   // 50,688 B
  __shared__ int IDX[32 * COLW];            // 8 KB
  const int t = threadIdx.x;
  const int rowBase = blockIdx.x * 32;

  ((int4*)IDX)[t] = ((const int4*)(csc + rowBase * COLW))[t];
  __syncthreads();

  { // gather + stage: 16 threads/row, 8 floats each; K = [msgs | hC?]
    const int r = t >> 4, sub = t & 15;
    const int c = rowBase + r;
    int cnt = ccnt[c]; if (cnt > COLW) cnt = COLW;
    const int* lst = IDX + r * COLW;
    float4 a0 = make_float4(0, 0, 0, 0), a1 = a0;
    int j = 0;
    for (; j + 8 <= cnt; j += 8) {
      float4 p0[8], p1[8];
      #pragma unroll
      for (int u = 0; u < 8; ++u) {
        const float4* s4 = (const float4*)(Lbuf + (size_t)lst[j + u] * DD) + sub * 2;
        p0[u] = s4[0]; p1[u] = s4[1];
      }
      #pragma unroll
      for (int u = 0; u < 8; ++u) { add4(a0, p0[u]); add4(a1, p1[u]); }
    }
    for (; j < cnt; ++j) {
      const float4* s4 = (const float4*)(Lbuf + (size_t)lst[j] * DD) + sub * 2;
      add4(a0, s4[0]); add4(a1, s4[1]);
    }
    store_oct3(A, sub, r, a0, a1);
    if constexpr (STAGE_H) {
      const float4* h4 = (const float4*)(hC + (size_t)c * DD) + sub * 2;
      store_oct3(A, 16 + sub, r, h4[0], h4[1]);
    }
  }
  __syncthreads();

  const int w = t >> 6, l = t & 63;
  const int quad = l >> 4, lane16 = l & 15;
  const int cw = w * 16 + lane16;
  f32x4 acc[2][4];
  #pragma unroll
  for (int mt = 0; mt < 2; ++mt)
    #pragma unroll
    for (int g = 0; g < 4; ++g) acc[mt][g] = (f32x4){0.f, 0.f, 0.f, 0.f};

  const short8* As = (const short8*)A;
  const short8* Bh = (const short8*)pkhi;
  const short8* Bm = (const short8*)pkmd;
  const short8* Bl = (const short8*)pklo;

  __builtin_amdgcn_s_setprio(1);   // T5 (R2: +1.2%)
  #pragma unroll
  for (int s = 0; s < NOCT / 4; ++s) {
    int ao = (s * 4 + quad) * OS + lane16;
    short8 a0h = As[ao],                a1h = As[ao + 16];
    short8 a0m = As[SPLITS8 + ao],      a1m = As[SPLITS8 + ao + 16];
    short8 a0l = As[2 * SPLITS8 + ao],  a1l = As[2 * SPLITS8 + ao + 16];
    int bo = (s * 4 + quad) * 512 + cw;
    #pragma unroll
    for (int g = 0; g < 4; ++g) {
      short8 bh = Bh[bo + g * 128];
      short8 bm = Bm[bo + g * 128];
      short8 bl = Bl[bo + g * 128];
      MFMA6(acc[0][g], a0h, a0m, a0l, bh, bm, bl);
      MFMA6(acc[1][g], a1h, a1m, a1l, bh, bm, bl);
    }
  }
  __builtin_amdgcn_s_setprio(0);
  clause_epilogue<false>(acc, bsum, bvec, ccnt, hC, Cs, rowBase, quad, cw);
}

template <int NOCT, bool STAGE_H>
__global__ __launch_bounds__(512, 2) void literal_bf3(
    const float* __restrict__ Cs, const int* __restrict__ csr, const int* __restrict__ rcnt,
    const unsigned short* __restrict__ pkhi, const unsigned short* __restrict__ pkmd,
    const unsigned short* __restrict__ pklo,
    const float* __restrict__ bsum, const float* __restrict__ bvec,
    float* __restrict__ hL, float* __restrict__ Lbuf) {
  __shared__ unsigned short A[3 * LSPL];    // 39,168 B
  __shared__ int IDX[16 * ROWW];            // 6 KB
  const int t = threadIdx.x;
  const int rowBase = blockIdx.x * 16;

  if (t < 384) ((int4*)IDX)[t] = ((const int4*)(csr + rowBase * ROWW))[t];
  __syncthreads();

  { // gather + stage: 32 threads/row, 4 floats each; K = [msgs | L | hL?]
    const int r = t >> 5, cg2 = t & 31;
    const int lr = rowBase + r;
    int cnt = rcnt[lr]; if (cnt > ROWW) cnt = ROWW;
    const int* lst = IDX + r * ROWW;
    float4 a0 = make_float4(0, 0, 0, 0);
    int j = 0;
    for (; j + 8 <= cnt; j += 8) {
      float4 p[8];
      #pragma unroll
      for (int u = 0; u < 8; ++u)
        p[u] = ((const float4*)(Cs + (size_t)lst[j + u] * DD))[cg2];
      #pragma unroll
      for (int u = 0; u < 8; ++u) add4(a0, p[u]);
    }
    for (; j < cnt; ++j)
      add4(a0, ((const float4*)(Cs + (size_t)lst[j] * DD))[cg2]);
    store_half3L(A, cg2 >> 1, cg2 & 1, r, a0);
    store_half3L(A, 16 + (cg2 >> 1), cg2 & 1, r,
                 ((const float4*)(Lbuf + (size_t)lr * DD))[cg2]);
    if constexpr (STAGE_H)
      store_half3L(A, 32 + (cg2 >> 1), cg2 & 1, r,
                   ((const float4*)(hL + (size_t)lr * DD))[cg2]);
  }
  __syncthreads();

  const int w = t >> 6, l = t & 63;
  const int quad = l >> 4, lane16 = l & 15;
  const int cw = w * 16 + lane16;
  f32x4 acc[4];
  #pragma unroll
  for (int g = 0; g < 4; ++g) acc[g] = (f32x4){0.f, 0.f, 0.f, 0.f};

  const short8* As = (const short8*)A;
  const short8* Bh = (const short8*)pkhi;
  const short8* Bm = (const short8*)pkmd;
  const short8* Bl = (const short8*)pklo;

  __builtin_amdgcn_s_setprio(1);   // T5
  #pragma unroll
  for (int s = 0; s < NOCT / 4; ++s) {
    int ao = (s * 4 + quad) * LSTR + lane16;
    short8 ah = As[ao];
    short8 am = As[LSPL / 8 + ao];
    short8 al = As[2 * (LSPL / 8) + ao];
    int bo = (s * 4 + quad) * 512 + cw;
    #pragma unroll
    for (int g = 0; g < 4; ++g) {
      short8 bh = Bh[bo + g * 128];
      short8 bm = Bm[bo + g * 128];
      short8 bl = Bl[bo + g * 128];
      MFMA6(acc[g], ah, am, al, bh, bm, bl);
    }
  }
  __builtin_amdgcn_s_setprio(0);

  float bs_[4], bv_[4];
  #pragma unroll
  for (int g = 0; g < 4; ++g) { bs_[g] = bsum[g * 128 + cw]; bv_[g] = bvec[g * 128 + cw]; }
  #pragma unroll
  for (int reg = 0; reg < 4; ++reg) {
    int row = rowBase + quad * 4 + reg;
    float deg = (float)rcnt[row];
    float co = hL[(size_t)row * DD + cw];
    float iv = acc[0][reg] + bs_[0] + deg * bv_[0];
    float fv = acc[1][reg] + bs_[1] + deg * bv_[1];
    float gv = acc[2][reg] + bs_[2] + deg * bv_[2];
    float ov = acc[3][reg] + bs_[3] + deg * bv_[3];
    float cn = sigm(fv) * co + sigm(iv) * tanh_(gv);
    hL[(size_t)row * DD + cw] = cn;
    Lbuf[(size_t)row * DD + cw] = sigm(ov) * tanh_(cn);
  }
}

// ---------------- fp16 3-term step kernels (steps NBF..7) ----------------

template <bool LAST>
__global__ __launch_bounds__(512, 2) void clause_f2(
    const float* __restrict__ Lbuf, const int* __restrict__ csc, const int* __restrict__ ccnt,
    const unsigned short* __restrict__ qkhi, const unsigned short* __restrict__ qklo,
    const float* __restrict__ bsum, const float* __restrict__ bvec,
    float* __restrict__ hC, float* __restrict__ Cs) {
  __shared__ unsigned short A[2 * SPLIT];   // 33,792 B
  __shared__ int IDX[32 * COLW];            // 8 KB
  const int t = threadIdx.x;
  const int rowBase = blockIdx.x * 32;

  ((int4*)IDX)[t] = ((const int4*)(csc + rowBase * COLW))[t];
  __syncthreads();

  {
    const int r = t >> 4, sub = t & 15;
    const int c = rowBase + r;
    int cnt = ccnt[c]; if (cnt > COLW) cnt = COLW;
    const int* lst = IDX + r * COLW;
    float4 a0 = make_float4(0, 0, 0, 0), a1 = a0;
    int j = 0;
    for (; j + 8 <= cnt; j += 8) {
      float4 p0[8], p1[8];
      #pragma unroll
      for (int u = 0; u < 8; ++u) {
        const float4* s4 = (const float4*)(Lbuf + (size_t)lst[j + u] * DD) + sub * 2;
        p0[u] = s4[0]; p1[u] = s4[1];
      }
      #pragma unroll
      for (int u = 0; u < 8; ++u) { add4(a0, p0[u]); add4(a1, p1[u]); }
    }
    for (; j < cnt; ++j) {
      const float4* s4 = (const float4*)(Lbuf + (size_t)lst[j] * DD) + sub * 2;
      add4(a0, s4[0]); add4(a1, s4[1]);
    }
    store_oct2g(A, OS, SPLIT, sub, r, a0, a1);
    const float4* h4 = (const float4*)(hC + (size_t)c * DD) + sub * 2;
    store_oct2g(A, OS, SPLIT, 16 + sub, r, h4[0], h4[1]);
  }
  __syncthreads();

  const int w = t >> 6, l = t & 63;
  const int quad = l >> 4, lane16 = l & 15;
  const int cw = w * 16 + lane16;
  f32x4 acc[2][4];
  #pragma unroll
  for (int mt = 0; mt < 2; ++mt)
    #pragma unroll
    for (int g = 0; g < 4; ++g) acc[mt][g] = (f32x4){0.f, 0.f, 0.f, 0.f};

  const half8* As = (const half8*)A;
  const half8* Bh = (const half8*)qkhi;
  const half8* Bl = (const half8*)qklo;

  __builtin_amdgcn_s_setprio(1);   // T5
  #pragma unroll
  for (int s = 0; s < 8; ++s) {
    int ao = (s * 4 + quad) * OS + lane16;
    half8 a0h = As[ao],           a1h = As[ao + 16];
    half8 a0l = As[SPLITS8 + ao], a1l = As[SPLITS8 + ao + 16];
    int bo = (s * 4 + quad) * 512 + cw;
    #pragma unroll
    for (int g = 0; g < 4; ++g) {
      half8 bh = Bh[bo + g * 128];
      half8 bl = Bl[bo + g * 128];
      MFMA3(acc[0][g], a0h, a0l, bh, bl);
      MFMA3(acc[1][g], a1h, a1l, bh, bl);
    }
  }
  __builtin_amdgcn_s_setprio(0);
  clause_epilogue<LAST>(acc, bsum, bvec, ccnt, hC, Cs, rowBase, quad, cw);
}

template <bool LAST>
__global__ __launch_bounds__(512, 2) void literal_f2(
    const float* __restrict__ Cs, const int* __restrict__ csr, const int* __restrict__ rcnt,
    const unsigned short* __restrict__ qkhi, const unsigned short* __restrict__ qklo,
    const float* __restrict__ bsum, const float* __restrict__ bvec,
    float* __restrict__ hL, float* __restrict__ Lbuf) {
  __shared__ unsigned short A[2 * L2SPL];   // 50,688 B
  __shared__ int IDX[32 * ROWW];            // 12 KB
  const int t = threadIdx.x;
  const int rowBase = blockIdx.x * 32;

  // stage index lists: 32 rows x 96 ints = 768 int4
  ((int4*)IDX)[t] = ((const int4*)(csr + rowBase * ROWW))[t];
  if (t < 256) ((int4*)IDX)[t + 512] = ((const int4*)(csr + rowBase * ROWW))[t + 512];
  __syncthreads();

  { // gather + stage: 16 threads/row, 8 floats each; K = [msgs | L | hL]
    const int r = t >> 4, sub = t & 15;
    const int lr = rowBase + r;
    int cnt = rcnt[lr]; if (cnt > ROWW) cnt = ROWW;
    const int* lst = IDX + r * ROWW;
    float4 a0 = make_float4(0, 0, 0, 0), a1 = a0;
    int j = 0;
    for (; j + 8 <= cnt; j += 8) {
      float4 p0[8], p1[8];
      #pragma unroll
      for (int u = 0; u < 8; ++u) {
        const float4* s4 = (const float4*)(Cs + (size_t)lst[j + u] * DD) + sub * 2;
        p0[u] = s4[0]; p1[u] = s4[1];
      }
      #pragma unroll
      for (int u = 0; u < 8; ++u) { add4(a0, p0[u]); add4(a1, p1[u]); }
    }
    for (; j < cnt; ++j) {
      const float4* s4 = (const float4*)(Cs + (size_t)lst[j] * DD) + sub * 2;
      add4(a0, s4[0]); add4(a1, s4[1]);
    }
    store_oct2g(A, L2S, L2SPL, sub, r, a0, a1);
    const float4* l4 = (const float4*)(Lbuf + (size_t)lr * DD) + sub * 2;
    store_oct2g(A, L2S, L2SPL, 16 + sub, r, l4[0], l4[1]);
    const float4* h4 = (const float4*)(hL + (size_t)lr * DD) + sub * 2;
    store_oct2g(A, L2S, L2SPL, 32 + sub, r, h4[0], h4[1]);
  }
  __syncthreads();

  const int w = t >> 6, l = t & 63;
  const int quad = l >> 4, lane16 = l & 15;
  const int cw = w * 16 + lane16;
  f32x4 acc[2][4];
  #pragma unroll
  for (int mt = 0; mt < 2; ++mt)
    #pragma unroll
    for (int g = 0; g < 4; ++g) acc[mt][g] = (f32x4){0.f, 0.f, 0.f, 0.f};

  const half8* As = (const half8*)A;        // idx = oct*L2S + m
  const half8* Bh = (const half8*)qkhi;
  const half8* Bl = (const half8*)qklo;

  __builtin_amdgcn_s_setprio(1);   // T5
  #pragma unroll
  for (int s = 0; s < 12; ++s) {            // K=384
    int ao = (s * 4 + quad) * L2S + lane16;
    half8 a0h = As[ao],             a1h = As[ao + 16];
    half8 a0l = As[L2SPL / 8 + ao], a1l = As[L2SPL / 8 + ao + 16];
    int bo = (s * 4 + quad) * 512 + cw;
    #pragma unroll
    for (int g = 0; g < 4; ++g) {
      half8 bh = Bh[bo + g * 128];
      half8 bl = Bl[bo + g * 128];
      MFMA3(acc[0][g], a0h, a0l, bh, bl);
      MFMA3(acc[1][g], a1h, a1l, bh, bl);
    }
  }
  __builtin_amdgcn_s_setprio(0);
  literal_epilogue2<LAST>(acc, bsum, bvec, rcnt, hL, Lbuf, rowBase, quad, cw);
}

// ---------------- launch ----------------

extern "C" void kernel_launch(void* const* d_in, const int* in_sizes, int n_in,
                              void* d_out, int out_size, void* d_ws, size_t ws_size,
                              hipStream_t stream) {
  const float* L0   = (const float*)d_in[0];
  // d_in[1] = C_state (unused), d_in[5] = n_vars (flip is identity)
  const float* hL0  = (const float*)d_in[2];
  const float* hC0  = (const float*)d_in[3];
  const float* M    = (const float*)d_in[4];
  const float* Wlc  = (const float*)d_in[6];
  const float* blc  = (const float*)d_in[7];
  const float* Wcl  = (const float*)d_in[8];
  const float* bcl  = (const float*)d_in[9];
  const float* WihC = (const float*)d_in[10];
  const float* WhhC = (const float*)d_in[11];
  const float* bihC = (const float*)d_in[12];
  const float* bhhC = (const float*)d_in[13];
  const float* WihL = (const float*)d_in[14];
  const float* WhhL = (const float*)d_in[15];
  const float* bihL = (const float*)d_in[16];
  const float* bhhL = (const float*)d_in[17];

  float* ws    = (float*)d_ws;
  float* hL    = ws;                         // NL*DD
  float* hC    = hL + NL * DD;               // NC*DD
  float* Cs    = hC + NC * DD;               // NC*DD
  float* bsumC = Cs + NC * DD;               // 512 each
  float* bvecC = bsumC + 512;
  float* bsumL = bvecC + 512;
  float* bvecL = bsumL + 512;
  unsigned short* pkChi = (unsigned short*)(bvecL + 512);   // bf16 clause: 3 x 256*512
  unsigned short* pkCmd = pkChi + 256 * 512;
  unsigned short* pkClo = pkCmd + 256 * 512;
  unsigned short* pkLhi = pkClo + 256 * 512;                // bf16 literal: 3 x 384*512
  unsigned short* pkLmd = pkLhi + 384 * 512;
  unsigned short* pkLlo = pkLmd + 384 * 512;
  unsigned short* qkChi = pkLlo + 384 * 512;                // fp16 clause: 2 x 256*512
  unsigned short* qkClo = qkChi + 256 * 512;
  unsigned short* qkLhi = qkClo + 256 * 512;                // fp16 literal: 2 x 384*512
  unsigned short* qkLlo = qkLhi + 384 * 512;
  int* csr  = (int*)(qkLlo + 384 * 512);     // NL*ROWW
  int* csc  = csr + NL * ROWW;               // NC*COLW
  int* rcnt = csc + NC * COLW;               // NL
  int* ccnt = rcnt + NL;                     // NC (contiguous with rcnt)
  float* Lbuf = (float*)d_out;               // literal state lives in d_out

  // build_all also zeroes rcnt|ccnt (doesn't read them); the dispatch boundary
  // before prep_graph orders zeroing ahead of the scan atomics. No memset.
  build_all<<<1284, 256, 0, stream>>>(WihC, Wlc, WhhC, blc, bihC, bhhC,
                                      WihL, Wcl, WhhL, bcl, bihL, bhhL,
                                      pkChi, pkCmd, pkClo, qkChi, qkClo,
                                      pkLhi, pkLmd, pkLlo, qkLhi, qkLlo,
                                      bsumC, bvecC, bsumL, bvecL, rcnt);

  prep_graph<<<4096, 256, 0, stream>>>((float4*)Lbuf, (const float4*)L0,
                                       (float4*)hL, (const float4*)hL0,
                                       (float4*)hC, (const float4*)hC0,
                                       (const float4*)M, csr, csc, rcnt, ccnt);

  // step 0: hidden states are zeros -> truncated K (exactly equivalent)
  clause_bf3<16, false><<<NC / 32, 512, 0, stream>>>(Lbuf, csc, ccnt, pkChi, pkCmd, pkClo,
                                                     bsumC, bvecC, hC, Cs);
  literal_bf3<32, false><<<NL / 16, 512, 0, stream>>>(Cs, csr, rcnt, pkLhi, pkLmd, pkLlo,
                                                      bsumL, bvecL, hL, Lbuf);
  // remaining bf16 steps
  for (int t = 1; t < NBF; ++t) {
    clause_bf3<32, true><<<NC / 32, 512, 0, stream>>>(Lbuf, csc, ccnt, pkChi, pkCmd, pkClo,
                                                      bsumC, bvecC, hC, Cs);
    literal_bf3<48, true><<<NL / 16, 512, 0, stream>>>(Cs, csr, rcnt, pkLhi, pkLmd, pkLlo,
                                                       bsumL, bvecL, hL, Lbuf);
  }
  // fp16 steps (step 7 skips dead hC/hL state stores)
  for (int t = NBF; t < TSTEPS; ++t) {
    if (t != TSTEPS - 1) {
      clause_f2<false><<<NC / 32, 512, 0, stream>>>(Lbuf, csc, ccnt, qkChi, qkClo,
                                                    bsumC, bvecC, hC, Cs);
      literal_f2<false><<<NL / 32, 512, 0, stream>>>(Cs, csr, rcnt, qkLhi, qkLlo,
                                                     bsumL, bvecL, hL, Lbuf);
    } else {
      clause_f2<true><<<NC / 32, 512, 0, stream>>>(Lbuf, csc, ccnt, qkChi, qkClo,
                                                   bsumC, bvecC, hC, Cs);
      literal_f2<true><<<NL / 32, 512, 0, stream>>>(Cs, csr, rcnt, qkLhi, qkLlo,
                                                    bsumL, bvecL, hL, Lbuf);
    }
  }
}